// Round 1
// baseline (207.096 us; speedup 1.0000x reference)
//
#include <hip/hip_runtime.h>

// CenterLoss forward: mean_b clamp( ||x_b - centers[labels_b]||^2, 1e-12, 1e12 )
// B=256, D=512, C=85742. Tiny, memory-trivial (~1 MB), launch-bound.
//
// Layout: 1 block per row, 128 threads (2 waves). Each thread handles one
// float4 (4 elems) of the 512-dim row -> coalesced 16 B/lane loads of both
// x and the gathered center row. Wave shuffle-reduce (width 64), combine the
// two waves through LDS, clamp, one atomicAdd per block scaled by 1/B.

#define BATCH 256
#define FEAT_DIM 512

__global__ __launch_bounds__(128) void center_loss_kernel(
    const float* __restrict__ x,
    const int* __restrict__ labels,
    const float* __restrict__ centers,
    float* __restrict__ out) {
  const int b = blockIdx.x;      // row
  const int t = threadIdx.x;     // 0..127

  const int lab = labels[b];
  const float4* xrow = reinterpret_cast<const float4*>(x + (size_t)b * FEAT_DIM);
  const float4* crow = reinterpret_cast<const float4*>(centers + (size_t)lab * FEAT_DIM);

  const float4 xv = xrow[t];
  const float4 cv = crow[t];
  const float d0 = xv.x - cv.x;
  const float d1 = xv.y - cv.y;
  const float d2 = xv.z - cv.z;
  const float d3 = xv.w - cv.w;
  float s = d0 * d0 + d1 * d1 + d2 * d2 + d3 * d3;

  // wave-64 butterfly reduce
  #pragma unroll
  for (int off = 32; off > 0; off >>= 1) s += __shfl_down(s, off, 64);

  __shared__ float wsum[2];
  if ((t & 63) == 0) wsum[t >> 6] = s;
  __syncthreads();

  if (t == 0) {
    float dist = wsum[0] + wsum[1];
    dist = fminf(fmaxf(dist, 1e-12f), 1e12f);
    atomicAdd(out, dist * (1.0f / (float)BATCH));
  }
}

extern "C" void kernel_launch(void* const* d_in, const int* in_sizes, int n_in,
                              void* d_out, int out_size, void* d_ws, size_t ws_size,
                              hipStream_t stream) {
  const float* x = (const float*)d_in[0];        // [256, 512] f32
  const int* labels = (const int*)d_in[1];       // [256] int32
  const float* centers = (const float*)d_in[2];  // [85742, 512] f32
  float* out = (float*)d_out;                    // scalar f32

  // d_out is re-poisoned to 0xAA before every timed launch; zero it
  // (stream-ordered, graph-capture-safe).
  hipMemsetAsync(out, 0, sizeof(float), stream);

  center_loss_kernel<<<BATCH, 128, 0, stream>>>(x, labels, centers, out);
}